// Round 1
// baseline (275.193 us; speedup 1.0000x reference)
//
#include <hip/hip_runtime.h>
#include <cstdint>
#include <cstddef>

#define H_CH 1024
#define NST  64
#define OUTF 512
#define LSEQ 4096

typedef __bf16 bf16x8 __attribute__((ext_vector_type(8)));
typedef float floatx4 __attribute__((ext_vector_type(4)));

__device__ __forceinline__ unsigned short f2bf(float f) {
    __bf16 b = (__bf16)f;                       // fptrunc = round-to-nearest-even
    return __builtin_bit_cast(unsigned short, b);
}

// ---------------------------------------------------------------------------
// Kernel 1: S4D recurrence + posenc + skip + GELU.  One wave per (b, c).
// Lane n = state n.  Output g (bf16) in (b, c, l) layout.
// ---------------------------------------------------------------------------
__global__ __launch_bounds__(128) void s4_scan_kernel(
    const float* __restrict__ x, const float* __restrict__ log_dt,
    const float* __restrict__ A_re, const float* __restrict__ A_im,
    const float* __restrict__ C_re, const float* __restrict__ C_im,
    const float* __restrict__ Dp, unsigned short* __restrict__ g_bcl)
{
    __shared__ float pbuf[2][64 * 65];          // per-wave 64x64 partials, stride 65
    const int w    = threadIdx.x >> 6;
    const int lane = threadIdx.x & 63;
    const int wid  = blockIdx.x * 2 + w;        // 0..2047
    const int b    = wid >> 10;
    const int c    = wid & 1023;

    // --- per-lane discretized SSM params (fp64 once; phase accuracy) ---
    const int idx = c * NST + lane;
    double are = (double)A_re[idx];
    double aim = (double)A_im[idx];
    double cre = (double)C_re[idx];
    double cim = (double)C_im[idx];
    double dt  = exp((double)log_dt[c]);
    double dar = dt * are, dai = dt * aim;
    double er  = exp(dar);
    double lre = er * cos(dai), lim = er * sin(dai);
    double nre = lre - 1.0, nim = lim;          // (lambda - 1)
    double d2  = are * are + aim * aim;
    double qre = (nre * are + nim * aim) / d2;  // (lambda-1)/A
    double qim = (nim * are - nre * aim) / d2;
    double ctre = cre * qre - cim * qim;        // Ct = C*(lambda-1)/A
    double ctim = cre * qim + cim * qre;
    const float lam_re = (float)lre, lam_im = (float)lim;
    const float c2r  = (float)( 2.0 * ctre);    // fold the 2*Re(...) into coeffs
    const float c2mi = (float)(-2.0 * ctim);
    const float Dc   = Dp[c];

    // --- positional-encoding params for this channel ---
    const int axis   = (c >= 684) ? 2 : ((c >= 342) ? 1 : 0);
    const int j      = c - 342 * axis;
    const float freq = (float)exp(-log(10000.0) * (double)(2 * (j >> 1)) / 342.0);
    const int is_cos = j & 1;

    const float* xp = x + ((size_t)b * H_CH + c) * (size_t)LSEQ;
    unsigned short* gp = g_bcl + ((size_t)b * H_CH + c) * (size_t)LSEQ;
    float* pw = &pbuf[w][0];

    float s_re = 0.f, s_im = 0.f;

    for (int chunk = 0; chunk < 64; ++chunk) {
        const int l0 = chunk * 64;
        const int l  = l0 + lane;
        int pos;
        if (axis == 0)      pos = l >> 8;
        else if (axis == 1) pos = (l >> 4) & 15;
        else                pos = l & 15;
        const float arg = (float)pos * freq;
        const float pe  = is_cos ? cosf(arg) : sinf(arg);
        const float vv  = xp[l] + pe;           // v = x + posenc, lane <-> l0+lane

        #pragma unroll
        for (int t = 0; t < 64; ++t) {
            // broadcast v[l0+t] to all lanes (uniform -> SGPR)
            float vt = __int_as_float(__builtin_amdgcn_readlane(__float_as_int(vv), t));
            float tre = fmaf(lam_re, s_re, fmaf(-lam_im, s_im, vt));
            float tim = fmaf(lam_re, s_im, lam_im * s_re);
            s_re = tre; s_im = tim;
            // partial contribution of state n to y[l0+t]
            pw[lane * 65 + t] = fmaf(c2r, s_re, c2mi * s_im);
        }
        // transpose-reduce: lane i sums column i (stride-65 rows -> conflict-free)
        float acc = 0.f;
        #pragma unroll
        for (int r = 0; r < 64; ++r) acc += pw[r * 65 + lane];

        float y = fmaf(Dc, vv, acc);            // + D * v skip
        float u = y + 0.044715f * y * y * y;    // tanh-approx GELU (jax default)
        float g = 0.5f * y * (1.f + tanhf(0.7978845608028654f * u));
        gp[l] = f2bf(g);
    }
}

// ---------------------------------------------------------------------------
// Kernel 2: transpose g (b,c,l) bf16 -> gT (b,l,c) bf16, 64x64 LDS tiles.
// ---------------------------------------------------------------------------
__global__ __launch_bounds__(256) void transpose_g_kernel(
    const unsigned short* __restrict__ g_bcl, unsigned short* __restrict__ gT)
{
    __shared__ unsigned int tileU[64 * 33];     // [c][l-pair], padded
    const int t  = threadIdx.x;
    const int ty = t >> 5;                      // 0..7
    const int tx = t & 31;                      // 0..31
    const int l0 = blockIdx.x * 64;
    const int c0 = blockIdx.y * 64;
    const int b  = blockIdx.z;

    #pragma unroll
    for (int r = 0; r < 8; ++r) {
        const int ci = r * 8 + ty;
        tileU[ci * 33 + tx] =
            *(const unsigned int*)&g_bcl[((size_t)b * H_CH + c0 + ci) * LSEQ + l0 + tx * 2];
    }
    __syncthreads();
    #pragma unroll
    for (int r = 0; r < 8; ++r) {
        const int li = r * 8 + ty;
        unsigned int ua = tileU[(2 * tx)     * 33 + (li >> 1)];
        unsigned int ub = tileU[(2 * tx + 1) * 33 + (li >> 1)];
        unsigned int s0 = (li & 1) ? (ua >> 16) : (ua & 0xffffu);
        unsigned int s1 = (li & 1) ? (ub >> 16) : (ub & 0xffffu);
        *(unsigned int*)&gT[((size_t)b * LSEQ + l0 + li) * H_CH + c0 + 2 * tx] =
            s0 | (s1 << 16);
    }
}

// ---------------------------------------------------------------------------
// Kernel 3: W (k=1024, o=512) fp32 -> Wt (o=512, k=1024) bf16.
// ---------------------------------------------------------------------------
__global__ __launch_bounds__(256) void transpose_w_kernel(
    const float* __restrict__ W, unsigned short* __restrict__ Wt)
{
    __shared__ float tileF[64 * 65];
    const int t  = threadIdx.x;
    const int o0 = blockIdx.x * 64;
    const int k0 = blockIdx.y * 64;
    {
        const int ty = t >> 6, tx = t & 63;
        #pragma unroll
        for (int r = 0; r < 16; ++r) {
            const int ki = r * 4 + ty;
            tileF[ki * 65 + tx] = W[(size_t)(k0 + ki) * OUTF + o0 + tx];
        }
    }
    __syncthreads();
    {
        const int ty = t >> 5, tx = t & 31;
        #pragma unroll
        for (int r = 0; r < 8; ++r) {
            const int oi = r * 8 + ty;
            unsigned int u0 = f2bf(tileF[(2 * tx)     * 65 + oi]);
            unsigned int u1 = f2bf(tileF[(2 * tx + 1) * 65 + oi]);
            *(unsigned int*)&Wt[(size_t)(o0 + oi) * H_CH + k0 + 2 * tx] = u0 | (u1 << 16);
        }
    }
}

// ---------------------------------------------------------------------------
// Kernel 4: out[b,o,l] = sum_k Wt[o,k]*gT[b,l,k] + b_out[o].
// 128x128x32 tiles, 4 waves of 64x64, mfma_f32_16x16x32_bf16.
// ---------------------------------------------------------------------------
__global__ __launch_bounds__(256) void gemm_kernel(
    const unsigned short* __restrict__ gT, const unsigned short* __restrict__ Wt,
    const float* __restrict__ b_out, float* __restrict__ out)
{
    __shared__ unsigned short As[128 * 40];     // [o-row][k], rows padded to 80 B
    __shared__ unsigned short Bs[128 * 40];     // [l-row][k]

    const int t    = threadIdx.x;
    const int lane = t & 63;
    const int wid  = t >> 6;
    const int wo   = wid & 1;                   // wave o-half
    const int wl   = wid >> 1;                  // wave l-half
    const int lm   = lane & 15;
    const int lq   = lane >> 4;

    const int l0 = blockIdx.x * 128;
    const int o0 = blockIdx.y * 128;
    const int bb = blockIdx.z;
    const unsigned short* gB = gT + (size_t)bb * LSEQ * H_CH;

    floatx4 acc[4][4];
    #pragma unroll
    for (int i = 0; i < 4; ++i)
        #pragma unroll
        for (int jj = 0; jj < 4; ++jj)
            acc[i][jj] = (floatx4){0.f, 0.f, 0.f, 0.f};

    for (int kt = 0; kt < 32; ++kt) {
        const int k0 = kt * 32;
        __syncthreads();                        // finish previous iter's reads
        #pragma unroll
        for (int half = 0; half < 2; ++half) {
            const int chunk = t + half * 256;   // 0..511
            const int row = chunk >> 2, q = chunk & 3;
            *(uint4*)&As[row * 40 + q * 8] =
                *(const uint4*)(Wt + (size_t)(o0 + row) * H_CH + k0 + q * 8);
            *(uint4*)&Bs[row * 40 + q * 8] =
                *(const uint4*)(gB + (size_t)(l0 + row) * H_CH + k0 + q * 8);
        }
        __syncthreads();

        bf16x8 af[4], bfr[4];
        #pragma unroll
        for (int sm = 0; sm < 4; ++sm)
            af[sm] = *(const bf16x8*)&As[(wo * 64 + sm * 16 + lm) * 40 + lq * 8];
        #pragma unroll
        for (int sn = 0; sn < 4; ++sn)
            bfr[sn] = *(const bf16x8*)&Bs[(wl * 64 + sn * 16 + lm) * 40 + lq * 8];

        #pragma unroll
        for (int sm = 0; sm < 4; ++sm)
            #pragma unroll
            for (int sn = 0; sn < 4; ++sn)
                acc[sm][sn] = __builtin_amdgcn_mfma_f32_16x16x32_bf16(
                    af[sm], bfr[sn], acc[sm][sn], 0, 0, 0);
    }

    float bias[4][4];
    #pragma unroll
    for (int sm = 0; sm < 4; ++sm)
        #pragma unroll
        for (int r = 0; r < 4; ++r)
            bias[sm][r] = b_out[o0 + wo * 64 + sm * 16 + lq * 4 + r];

    #pragma unroll
    for (int sm = 0; sm < 4; ++sm)
        #pragma unroll
        for (int sn = 0; sn < 4; ++sn)
            #pragma unroll
            for (int r = 0; r < 4; ++r) {
                const int o = o0 + wo * 64 + sm * 16 + lq * 4 + r;   // D row = m
                const int l = l0 + wl * 64 + sn * 16 + lm;           // D col = n
                out[((size_t)bb * OUTF + o) * LSEQ + l] = acc[sm][sn][r] + bias[sm][r];
            }
}

// ---------------------------------------------------------------------------
extern "C" void kernel_launch(void* const* d_in, const int* in_sizes, int n_in,
                              void* d_out, int out_size, void* d_ws, size_t ws_size,
                              hipStream_t stream) {
    const float* x      = (const float*)d_in[0];
    const float* log_dt = (const float*)d_in[1];
    const float* A_re   = (const float*)d_in[2];
    const float* A_im   = (const float*)d_in[3];
    const float* C_re   = (const float*)d_in[4];
    const float* C_im   = (const float*)d_in[5];
    const float* Dp     = (const float*)d_in[6];
    const float* W_out  = (const float*)d_in[7];
    const float* b_out  = (const float*)d_in[8];
    float* out = (float*)d_out;

    char* ws = (char*)d_ws;
    unsigned short* g_bcl = (unsigned short*)ws;                              // 16 MiB
    unsigned short* gT    = (unsigned short*)(ws + (size_t)16 * 1024 * 1024); // 16 MiB
    unsigned short* Wt    = (unsigned short*)(ws + (size_t)32 * 1024 * 1024); // 1 MiB

    s4_scan_kernel<<<1024, 128, 0, stream>>>(x, log_dt, A_re, A_im, C_re, C_im,
                                             Dp, g_bcl);
    transpose_g_kernel<<<dim3(64, 16, 2), 256, 0, stream>>>(g_bcl, gT);
    transpose_w_kernel<<<dim3(8, 16), 256, 0, stream>>>(W_out, Wt);
    gemm_kernel<<<dim3(32, 4, 2), 256, 0, stream>>>(gT, Wt, b_out, out);
}